// Round 6
// baseline (14825.319 us; speedup 1.0000x reference)
//
#include <hip/hip_runtime.h>
#include <math.h>

// Problem constants (V,E,H,K,T,B) = (32000, 512, 512, 32, 256, 64)
#define T_STEPS 256
#define BATCH   64
#define HID     512
#define EMB     512
#define KTAGS   32
#define NEGV    -100000.0f
#define START_TAG 30
#define END_TAG   31

#define NBLK_DIR  32          // blocks per direction (64 total)
#define SPIN_LIM  (1 << 26)

typedef __attribute__((ext_vector_type(8))) short short8;
typedef __attribute__((ext_vector_type(4))) float f32x4;

union V16 { uint4 u; short8 s; };
union HQ  { unsigned long long q[2]; short8 s; };

static __device__ __forceinline__ unsigned short f2b(float f) {
    unsigned u = __float_as_uint(f);
    return (unsigned short)((u + 0x7fffu + ((u >> 16) & 1u)) >> 16);
}
static __device__ __forceinline__ float b2f(unsigned short us) {
    return __uint_as_float(((unsigned)us) << 16);
}
static __device__ __forceinline__ float sigf(float x) {
    return 1.0f / (1.0f + __expf(-x));
}

// ---------------------------------------------------------------------------
// Zero flags (agent-scope stores: step kernels read them via atomics that
// bypass the non-coherent L2) + output scalar.
// ---------------------------------------------------------------------------
__global__ __launch_bounds__(256) void init_zero(unsigned int* __restrict__ flags,
                                                 float* __restrict__ out)
{
    int i = blockIdx.x * 256 + threadIdx.x;
    if (i < 1028)
        __hip_atomic_store(flags + i, 0u, __ATOMIC_RELAXED, __HIP_MEMORY_SCOPE_AGENT);
    if (i == 0)
        __hip_atomic_store(out, 0.0f, __ATOMIC_RELAXED, __HIP_MEMORY_SCOPE_AGENT);
}

// ---------------------------------------------------------------------------
// embed fp32 -> bf16
// ---------------------------------------------------------------------------
__global__ __launch_bounds__(256) void convert_embed(const float* __restrict__ src,
                                                     unsigned short* __restrict__ dst)
{
    long long i = ((long long)blockIdx.x * 256 + threadIdx.x) * 4;
    if (i >= (long long)32000 * 512) return;
    float4 v = *(const float4*)(src + i);
    ushort4 o;
    o.x = f2b(v.x); o.y = f2b(v.y); o.z = f2b(v.z); o.w = f2b(v.w);
    *(ushort4*)(dst + i) = o;
}

// ---------------------------------------------------------------------------
// Pack Wih|Whh (fp32) into per-wave register-resident bf16 B-fragment stream.
// Stream: [d(2)][nt(32)][g(4)][kh(2)][kfi(NKW)][lane(64)][j(8)]
//   block (d,nt) owns h-cols nt*16..+15; wave (g,kh) owns gate g, K-half kh.
//   kfi < NKX (=XKT/2): x-part, global kfrag kt = kh*NKX+kfi (from Wih)
//   kfi >= NKX:         h-part, h-kfrag = kh*8 + (kfi-NKX)   (from Whh)
//   B-frag element: n = lane&15 -> weight row r = g*512 + nt*16 + n;
//                   k = kt*32 + (lane>>4)*8 + j.
// ---------------------------------------------------------------------------
__global__ __launch_bounds__(256) void pack_w(const float* __restrict__ wih,
                                              const float* __restrict__ whh,
                                              int xK,
                                              unsigned short* __restrict__ wpack)
{
    const int XKT = xK >> 5, NKX = XKT >> 1, NKW = NKX + 8;
    long long t = (long long)blockIdx.x * 256 + threadIdx.x;
    if (t >= (long long)512 * NKW * 64) return;
    int lane = (int)(t & 63);
    long long rest = t >> 6;
    int kfi = (int)(rest % NKW); rest /= NKW;
    int kh = (int)(rest & 1); rest >>= 1;
    int g  = (int)(rest & 3); rest >>= 2;
    int nt = (int)(rest & 31);
    int d  = (int)(rest >> 5);
    int n = lane & 15, q = lane >> 4;
    int r = g * 512 + nt * 16 + n;
    const float* src;
    if (kfi < NKX)
        src = wih + (long long)d * 2048 * xK + (long long)r * xK + (kh * NKX + kfi) * 32 + q * 8;
    else
        src = whh + (long long)d * 2048 * 512 + (long long)r * 512 + (kh * 8 + (kfi - NKX)) * 32 + q * 8;
    float4 v0 = *(const float4*)src;
    float4 v1 = *(const float4*)(src + 4);
    unsigned short o[8] = { f2b(v0.x), f2b(v0.y), f2b(v0.z), f2b(v0.w),
                            f2b(v1.x), f2b(v1.y), f2b(v1.z), f2b(v1.w) };
    *(uint4*)(wpack + t * 8) = *(const uint4*)o;
}

// ---------------------------------------------------------------------------
// One BiLSTM layer, persistent: 64 blocks (d=bid&1, nt=bid>>1) x 512 threads.
// Wave w: g=w>>1 (gate), kh=w&1 (K-half). Weights live in REGISTERS for the
// whole launch (zero weight mem traffic in the step loop). Per step:
//   X phase (no h dep): A-frags straight from global bf16 rows -> MFMA.
//   flag wait -> H phase: h_prev via relaxed agent u64 atomics (IF-coherent).
//   kh-pair reduce through LDS -> gates (c-state in regs) -> h stores:
//   u32 agent atomic to hbuf + normal u32 to hs_out; vmcnt drain; flag add.
// Layer barrier / hs publication = kernel boundary (no threadfence anywhere).
// ---------------------------------------------------------------------------
template<int XKT>   // 16 (L0, xK=512) or 32 (L1, xK=1024)
__global__ __launch_bounds__(512, 2) void lstm_layer(
    const int* __restrict__ tokens,          // L0 only
    const unsigned short* __restrict__ xsrc, // embB (L0) or hs0 (L1)
    const unsigned short* __restrict__ wp,   // packed weights
    const float* __restrict__ bias,          // [2][2048]
    unsigned short* __restrict__ hso,        // [T][64][1024] bf16 out
    unsigned long long* __restrict__ hbuf64, // [2 par][2 d][64][128] u64
    unsigned int* __restrict__ flags)        // [2 d][256]
{
    constexpr int NKX = XKT / 2;
    constexpr int NKW = NKX + 8;
    __shared__ int   tok_s[64];
    __shared__ float Gp[4][64][17];

    const int bid = blockIdx.x;
    const int d   = bid & 1;
    const int nt  = bid >> 1;           // 0..31 -> h-cols nt*16..+15
    const int tid = threadIdx.x;
    const int w   = tid >> 6, lane = tid & 63;
    const int g   = w >> 1, kh = w & 1;
    const int lm  = lane & 15, q = lane >> 4;
    const int gb  = tid >> 3, hcl = (tid & 7) * 2;   // gate-phase cell (b, 2 h-cols)

    // ---- weights -> registers (once per launch) ----
    const unsigned short* wb = wp + (long long)(((d * 32 + nt) * 4 + g) * 2 + kh) * NKW * 512;
    short8 wx[NKX], wh[8];
    #pragma unroll
    for (int i = 0; i < NKX; ++i) { V16 t; t.u = *(const uint4*)(wb + i * 512 + lane * 8); wx[i] = t.s; }
    #pragma unroll
    for (int i = 0; i < 8; ++i)   { V16 t; t.u = *(const uint4*)(wb + (NKX + i) * 512 + lane * 8); wh[i] = t.s; }

    float bz[8];
    #pragma unroll
    for (int gg = 0; gg < 4; ++gg) {
        bz[gg * 2 + 0] = bias[d * 2048 + gg * 512 + nt * 16 + hcl + 0];
        bz[gg * 2 + 1] = bias[d * 2048 + gg * 512 + nt * 16 + hcl + 1];
    }
    float c0 = 0.0f, c1 = 0.0f;
    unsigned int* flagp = flags + d * 256;
    unsigned int* hb32  = (unsigned int*)hbuf64;
    bool dead = false;

    for (int s = 0; s < T_STEPS; ++s) {
        const int tt = d ? (T_STEPS - 1 - s) : s;

        if (XKT == 16) {
            if (tid < 64) tok_s[tid] = tokens[tt * BATCH + tid];
            __syncthreads();
        }

        f32x4 acc[4];
        #pragma unroll
        for (int mt = 0; mt < 4; ++mt) acc[mt] = (f32x4)0.0f;

        const unsigned short* xr[4];
        #pragma unroll
        for (int mt = 0; mt < 4; ++mt) {
            int m = mt * 16 + lm;
            if (XKT == 16) xr[mt] = xsrc + (long long)tok_s[m] * 512;
            else           xr[mt] = xsrc + ((long long)tt * BATCH + m) * 1024;
        }

        // ---------------- X phase (no h dependency) -------------------------
        #pragma unroll
        for (int i = 0; i < NKX; ++i) {
            const int kt = kh * NKX + i;
            #pragma unroll
            for (int mt = 0; mt < 4; ++mt) {
                V16 av; av.u = *(const uint4*)(xr[mt] + kt * 32 + q * 8);
                acc[mt] = __builtin_amdgcn_mfma_f32_16x16x32_bf16(av.s, wx[i], acc[mt], 0, 0, 0);
            }
        }

        // ---------------- wait h(s-1), H phase ------------------------------
        if (s > 0) {
            if (tid == 0 && !dead) {
                int n = 0;
                while (__hip_atomic_load(flagp + (s - 1), __ATOMIC_RELAXED,
                                         __HIP_MEMORY_SCOPE_AGENT) < (unsigned)NBLK_DIR) {
                    __builtin_amdgcn_s_sleep(1);
                    if (++n > SPIN_LIM) { dead = true; break; }
                }
            }
            __syncthreads();
            const int par = (s - 1) & 1;
            const unsigned long long* hb = hbuf64 + (long long)(par * 2 + d) * 64 * 128;
            #pragma unroll
            for (int i = 0; i < 8; ++i) {
                #pragma unroll
                for (int mt = 0; mt < 4; ++mt) {
                    const int m = mt * 16 + lm;
                    const long long o = (long long)m * 128 + (kh * 8 + i) * 8 + q * 2;
                    HQ h;
                    h.q[0] = __hip_atomic_load(hb + o,     __ATOMIC_RELAXED, __HIP_MEMORY_SCOPE_AGENT);
                    h.q[1] = __hip_atomic_load(hb + o + 1, __ATOMIC_RELAXED, __HIP_MEMORY_SCOPE_AGENT);
                    acc[mt] = __builtin_amdgcn_mfma_f32_16x16x32_bf16(h.s, wh[i], acc[mt], 0, 0, 0);
                }
            }
        }

        // ---------------- kh-pair K-reduce through LDS ----------------------
        if (kh) {
            #pragma unroll
            for (int mt = 0; mt < 4; ++mt)
                #pragma unroll
                for (int r = 0; r < 4; ++r)
                    Gp[g][mt * 16 + q * 4 + r][lm] = acc[mt][r];
        }
        __syncthreads();
        if (!kh) {
            #pragma unroll
            for (int mt = 0; mt < 4; ++mt)
                #pragma unroll
                for (int r = 0; r < 4; ++r)
                    Gp[g][mt * 16 + q * 4 + r][lm] += acc[mt][r];
        }
        __syncthreads();

        // ---------------- gates: 2 cells per thread -------------------------
        const float vi0 = Gp[0][gb][hcl]     + bz[0];
        const float vi1 = Gp[0][gb][hcl + 1] + bz[1];
        const float vf0 = Gp[1][gb][hcl]     + bz[2];
        const float vf1 = Gp[1][gb][hcl + 1] + bz[3];
        const float vg0 = Gp[2][gb][hcl]     + bz[4];
        const float vg1 = Gp[2][gb][hcl + 1] + bz[5];
        const float vo0 = Gp[3][gb][hcl]     + bz[6];
        const float vo1 = Gp[3][gb][hcl + 1] + bz[7];
        c0 = sigf(vf0) * c0 + sigf(vi0) * tanhf(vg0);
        c1 = sigf(vf1) * c1 + sigf(vi1) * tanhf(vg1);
        const float h0 = sigf(vo0) * tanhf(c0);
        const float h1 = sigf(vo1) * tanhf(c1);
        const unsigned int hv = (unsigned int)f2b(h0) | ((unsigned int)f2b(h1) << 16);

        __hip_atomic_store(&hb32[(long long)((s & 1) * 2 + d) * 16384 + gb * 256 + nt * 8 + (hcl >> 1)],
                           hv, __ATOMIC_RELAXED, __HIP_MEMORY_SCOPE_AGENT);
        ((unsigned int*)hso)[(((long long)tt * BATCH + gb) * 1024 + d * 512 + nt * 16 + hcl) >> 1] = hv;

        asm volatile("s_waitcnt vmcnt(0)" ::: "memory");
        __syncthreads();
        if (tid == 0)
            __hip_atomic_fetch_add(flagp + s, 1u, __ATOMIC_RELAXED, __HIP_MEMORY_SCOPE_AGENT);
    }
}

// ---------------------------------------------------------------------------
// feats = hs1(bf16) @ lin_w^T + lin_b   (64-row tiles, N=32)
// ---------------------------------------------------------------------------
__global__ __launch_bounds__(256) void gemm_feats(
    const unsigned short* __restrict__ A,      // [M][1024] bf16
    const float* __restrict__ W,               // [32][1024]
    const float* __restrict__ bias,
    float* __restrict__ C,
    int M, int N, int K)
{
    __shared__ __align__(16) float As[64][34];
    __shared__ __align__(16) float Ws[32][68];

    const int m0 = blockIdx.y * 64;
    const int tid = threadIdx.x;
    const int tr = tid >> 4;
    const int tc = tid & 15;

    float acc[4][4];
    #pragma unroll
    for (int i = 0; i < 4; ++i)
        #pragma unroll
        for (int j = 0; j < 4; ++j) acc[i][j] = 0.0f;

    for (int k0 = 0; k0 < K; k0 += 32) {
        {   // A tile: 64 rows x 32 k (bf16 -> f32)
            int row = tid >> 2, g8 = tid & 3;
            uint4 v = *(const uint4*)(A + ((long long)(m0 + row)) * 1024 + k0 + g8 * 8);
            const unsigned short* pv = (const unsigned short*)&v;
            #pragma unroll
            for (int e = 0; e < 8; ++e) As[row][g8 * 8 + e] = b2f(pv[e]);
        }
        {   // W tile: 32 rows x 32 k, transposed
            int row = tid >> 3, q2 = tid & 7;
            float4 v = *(const float4*)(W + (long long)row * K + k0 + 4 * q2);
            Ws[4*q2+0][row] = v.x; Ws[4*q2+1][row] = v.y;
            Ws[4*q2+2][row] = v.z; Ws[4*q2+3][row] = v.w;
        }
        __syncthreads();
        #pragma unroll 8
        for (int kk = 0; kk < 32; ++kk) {
            float a0 = As[4*tr+0][kk], a1 = As[4*tr+1][kk];
            float a2 = As[4*tr+2][kk], a3 = As[4*tr+3][kk];
            float4 wv = *(const float4*)&Ws[kk][4*tc];
            acc[0][0] += a0*wv.x; acc[0][1] += a0*wv.y; acc[0][2] += a0*wv.z; acc[0][3] += a0*wv.w;
            acc[1][0] += a1*wv.x; acc[1][1] += a1*wv.y; acc[1][2] += a1*wv.z; acc[1][3] += a1*wv.w;
            acc[2][0] += a2*wv.x; acc[2][1] += a2*wv.y; acc[2][2] += a2*wv.z; acc[2][3] += a2*wv.w;
            acc[3][0] += a3*wv.x; acc[3][1] += a3*wv.y; acc[3][2] += a3*wv.z; acc[3][3] += a3*wv.w;
        }
        __syncthreads();
    }
    #pragma unroll
    for (int i = 0; i < 4; ++i) {
        int m = m0 + 4*tr + i;
        #pragma unroll
        for (int j = 0; j < 4; ++j) {
            int n = 4*tc + j;
            if (n < N) C[(long long)m * N + n] = acc[i][j] + bias[n];
        }
    }
}

// ---------------------------------------------------------------------------
// CRF: forward logsumexp scan + log_z + gold score + loss, one block per b.
// ---------------------------------------------------------------------------
__global__ __launch_bounds__(1024) void crf_kernel(
    const float* __restrict__ feats,
    const float* __restrict__ trans,
    const int*   __restrict__ tokens,
    const int*   __restrict__ tags,
    const int*   __restrict__ lengths,
    float* __restrict__ out)
{
    const int b = blockIdx.x;
    const int tid = threadIdx.x;
    __shared__ float tr_s[KTAGS*KTAGS];
    __shared__ float score_s[KTAGS];
    __shared__ float emit_s[KTAGS];
    __shared__ float red_s[16];
    __shared__ float logz_s;

    tr_s[tid] = trans[tid];
    if (tid < KTAGS) score_s[tid] = (tid == START_TAG) ? 0.0f : NEGV;
    __syncthreads();

    const int i = tid >> 5, j = tid & 31;
    for (int t = 0; t < T_STEPS; ++t) {
        if (tid < KTAGS) emit_s[tid] = feats[((long long)t*BATCH + b)*KTAGS + tid];
        __syncthreads();
        float e = score_s[j] + tr_s[i*KTAGS + j];
        float m = e;
        m = fmaxf(m, __shfl_xor(m, 1));  m = fmaxf(m, __shfl_xor(m, 2));
        m = fmaxf(m, __shfl_xor(m, 4));  m = fmaxf(m, __shfl_xor(m, 8));
        m = fmaxf(m, __shfl_xor(m, 16));
        float p = __expf(e - m);
        p += __shfl_xor(p, 1); p += __shfl_xor(p, 2); p += __shfl_xor(p, 4);
        p += __shfl_xor(p, 8); p += __shfl_xor(p, 16);
        float nv = m + __logf(p) + emit_s[i];
        int msk = tokens[(long long)t*BATCH + b] > 0;
        __syncthreads();
        if (j == 0) score_s[i] = msk ? nv : score_s[i];
        __syncthreads();
    }

    if (tid < KTAGS) {
        float v = score_s[tid] + tr_s[END_TAG*KTAGS + tid];
        float m = v;
        m = fmaxf(m, __shfl_xor(m, 1));  m = fmaxf(m, __shfl_xor(m, 2));
        m = fmaxf(m, __shfl_xor(m, 4));  m = fmaxf(m, __shfl_xor(m, 8));
        m = fmaxf(m, __shfl_xor(m, 16));
        float p = __expf(v - m);
        p += __shfl_xor(p, 1); p += __shfl_xor(p, 2); p += __shfl_xor(p, 4);
        p += __shfl_xor(p, 8); p += __shfl_xor(p, 16);
        if (tid == 0) logz_s = m + __logf(p);
    }
    __syncthreads();

    float val = 0.0f;
    if (tid < T_STEPS) {
        int t = tid;
        int cur  = tags[(long long)t*BATCH + b];
        int prev = (t == 0) ? START_TAG : tags[(long long)(t-1)*BATCH + b];
        int msk  = tokens[(long long)t*BATCH + b] > 0;
        if (msk) val = tr_s[cur*KTAGS + prev]
                     + feats[((long long)t*BATCH + b)*KTAGS + cur];
    }
    val += __shfl_xor(val, 1);  val += __shfl_xor(val, 2);
    val += __shfl_xor(val, 4);  val += __shfl_xor(val, 8);
    val += __shfl_xor(val, 16); val += __shfl_xor(val, 32);
    int wave = tid >> 6, lane = tid & 63;
    if (lane == 0) red_s[wave] = val;
    __syncthreads();
    if (tid == 0) {
        float gsum = 0.0f;
        #pragma unroll
        for (int ww = 0; ww < 16; ++ww) gsum += red_s[ww];
        gsum += tr_s[END_TAG*KTAGS + tags[(long long)(T_STEPS-1)*BATCH + b]];
        atomicAdd(out, (logz_s - gsum) / (float)lengths[b]);
    }
}

// ---------------------------------------------------------------------------
extern "C" void kernel_launch(void* const* d_in, const int* in_sizes, int n_in,
                              void* d_out, int out_size, void* d_ws, size_t ws_size,
                              hipStream_t stream) {
    const int*   tokens  = (const int*)  d_in[0];
    const int*   tags    = (const int*)  d_in[1];
    const int*   lengths = (const int*)  d_in[2];
    const float* embed   = (const float*)d_in[3];
    const float* wih0    = (const float*)d_in[4];
    const float* whh0    = (const float*)d_in[5];
    const float* b0      = (const float*)d_in[6];
    const float* wih1    = (const float*)d_in[7];
    const float* whh1    = (const float*)d_in[8];
    const float* b1      = (const float*)d_in[9];
    const float* lin_w   = (const float*)d_in[10];
    const float* lin_b   = (const float*)d_in[11];
    const float* trans   = (const float*)d_in[12];

    // Workspace layout (~123.2 MiB)
    char* ws = (char*)d_ws;
    unsigned short* hs0   = (unsigned short*)(ws);                   // 33,554,432
    unsigned short* hs1   = (unsigned short*)(ws +  33554432ULL);    // 33,554,432
    unsigned short* embB  = (unsigned short*)(ws +  67108864ULL);    // 32,768,000
    unsigned short* wp0   = (unsigned short*)(ws +  99876864ULL);    //  8,388,608
    unsigned short* wp1   = (unsigned short*)(ws + 108265472ULL);    // 12,582,912
    float*          feats = (float*)        (ws + 120848384ULL);     //  2,097,152
    unsigned long long* hbuf = (unsigned long long*)(ws + 122945536ULL); // 262,144
    unsigned int*   flags = (unsigned int*) (ws + 123207680ULL);     //  4,096

    float* out = (float*)d_out;

    init_zero<<<dim3(5), 256, 0, stream>>>(flags, out);
    convert_embed<<<dim3(16000), 256, 0, stream>>>(embed, embB);
    pack_w<<<dim3(2048), 256, 0, stream>>>(wih0, whh0, 512,  wp0);
    pack_w<<<dim3(3072), 256, 0, stream>>>(wih1, whh1, 1024, wp1);

    // Layer 0 (xK=512): x = embB[tokens]; layer barrier = kernel boundary
    lstm_layer<16><<<dim3(2 * NBLK_DIR), 512, 0, stream>>>(
        tokens, embB, wp0, b0, hs0, hbuf, flags);

    // Layer 1 (xK=1024): x = hs0
    lstm_layer<32><<<dim3(2 * NBLK_DIR), 512, 0, stream>>>(
        nullptr, hs0, wp1, b1, hs1, hbuf, flags + 512);

    gemm_feats<<<dim3(1, 256, 1), 256, 0, stream>>>(
        hs1, lin_w, lin_b, feats, T_STEPS*BATCH, KTAGS, 2*HID);

    crf_kernel<<<dim3(BATCH), 1024, 0, stream>>>(feats, trans, tokens, tags,
                                                 lengths, out);
}